// Round 6
// baseline (197.951 us; speedup 1.0000x reference)
//
#include <hip/hip_runtime.h>

// Problem constants: B=1, L=320, D=128, H=4, DH=32
#define LQ 320
#define NSEQ 320
#define NROWS (NSEQ*LQ)   // 102400
#define DDIM 128
#define NH 4
#define DHD 32
#define LN_EPS 1e-5f
// 1/sqrt(32) * log2(e): folded into q so QK^T scores are in log2 domain
#define QSC2 0.25508652025545527f

typedef __bf16 bf16x8 __attribute__((ext_vector_type(8)));
typedef __bf16 bf16x2 __attribute__((ext_vector_type(2)));
typedef float f32x4 __attribute__((ext_vector_type(4)));
typedef float f32x16 __attribute__((ext_vector_type(16)));
union FragU { unsigned int u[4]; bf16x8 v; };

// key-compaction tables (mask is over keys, shared by all rows)
__device__ int g_inv[LQ];     // compact slot -> key position (pad slots -> 0)
__device__ int g_cnt;         // number of kept keys
// pre-converted bf16 weights in MFMA FRAGMENT order:
// uint4 chunk cid = ((s4*4 + kt)*8 + nt)*64 + lane holds
// W row (s4*128 + nt*16 + (lane&15)), cols kt*32 + (lane>>4)*8 .. +7.
// s4: 0,1,2 = w_qkv q/k/v chunks, 3 = w_out.
__device__ __align__(16) unsigned short g_wbf[512 * DDIM];

// native bf16 converts: compiler lowers paired casts to v_cvt_pk_bf16_f32
__device__ inline unsigned short f2bf(float f) {
    return __builtin_bit_cast(unsigned short, (__bf16)f);
}
__device__ inline unsigned int pack2(float a, float b) {
    bf16x2 t;
    t[0] = (__bf16)a;
    t[1] = (__bf16)b;
    return __builtin_bit_cast(unsigned int, t);
}
// 2x2 lane-block transpose: a <- [a.lo | b.lo], b <- [a.hi | b.hi]
__device__ inline void pl32swap(unsigned int &a, unsigned int &b) {
    asm volatile("v_permlane32_swap_b32 %0, %1" : "+v"(a), "+v"(b));
}

// =====================================================================
// K0: LayerNorm -> zn bf16 [row][128]. Grid 1600, block 256.
// Side jobs: block 0 wave 0: mask scan -> g_inv / g_cnt;
// blocks 1..32: W fp32 -> bf16 into g_wbf in FRAGMENT order.
// =====================================================================
__global__ __launch_bounds__(256) void k0_ln(
    const float* __restrict__ z, const float* __restrict__ ln_g, const float* __restrict__ ln_b,
    unsigned int* __restrict__ znws, const int* __restrict__ mask,
    const float* __restrict__ w_qkv, const float* __restrict__ w_out)
{
    const int tid = threadIdx.x;
    const int bx = blockIdx.x;
    const int rowbase = bx * 64;
    const int lane = tid & 63;
    const int wid = tid >> 6;

    if (bx == 0) {
        if (tid < 64) {
            int carry = 0;
            #pragma unroll 1
            for (int c = 0; c < 5; ++c) {
                const int i = c * 64 + tid;
                const int m = (mask[i] > 0) ? 1 : 0;
                int v = m;
                #pragma unroll
                for (int off = 1; off < 64; off <<= 1) {
                    const int o = __shfl_up(v, off, 64);
                    if (tid >= off) v += o;
                }
                v += carry;
                if (m) g_inv[v - 1] = i;
                carry = __shfl(v, 63, 64);
            }
            if (tid == 0) g_cnt = carry;
            for (int s = carry + tid; s < LQ; s += 64) g_inv[s] = 0;  // pad slots
        }
    } else if (bx <= 32) {
        // fragment-order W conversion: one uint4 chunk per thread
        const int cid = (bx - 1) * 256 + tid;   // 0..8191
        const int l2  = cid & 63;
        const int nt  = (cid >> 6) & 7;
        const int kt  = (cid >> 9) & 3;
        const int s4  = cid >> 11;              // 0..3
        const int qn2 = l2 & 15, gd2 = l2 >> 4;
        const int row = s4 * 128 + nt * 16 + qn2;       // 0..511
        const float4* src4 = (s4 < 3) ? (const float4*)w_qkv : (const float4*)w_out;
        const int rloc = (s4 < 3) ? row : (row - 384);
        const int fi = rloc * 32 + kt * 8 + gd2 * 2;
        const float4 a = src4[fi];
        const float4 b = src4[fi + 1];
        uint4 val;
        val.x = pack2(a.x, a.y);
        val.y = pack2(a.z, a.w);
        val.z = pack2(b.x, b.y);
        val.w = pack2(b.z, b.w);
        ((uint4*)g_wbf)[cid] = val;
    }

    const float g0 = ln_g[2 * lane], g1 = ln_g[2 * lane + 1];
    const float bb0 = ln_b[2 * lane], bb1 = ln_b[2 * lane + 1];
    #pragma unroll 1
    for (int r = wid; r < 64; r += 4) {
        const int row = rowbase + r;
        const float2 v = *(const float2*)(z + (size_t)row * DDIM + 2 * lane);
        float s = v.x + v.y;
        float s2 = v.x * v.x + v.y * v.y;
        #pragma unroll
        for (int off = 32; off > 0; off >>= 1) {
            s  += __shfl_xor(s, off, 64);
            s2 += __shfl_xor(s2, off, 64);
        }
        const float mu = s * (1.0f / 128.0f);
        const float var = s2 * (1.0f / 128.0f) - mu * mu;
        const float rs = rsqrtf(var + LN_EPS);
        znws[(size_t)row * 64 + lane] =
            pack2((v.x - mu) * rs * g0 + bb0, (v.y - mu) * rs * g1 + bb1);
    }
}

// =====================================================================
// K1: QKV GEMM, 3-way N-split. Grid 2400 (sect = bx%3, m = bx/3), block 256.
// Round-6: ALL 8 A-frags prefetched from global BEFORE the W-stage
// barrier (T14 issue-early: ~300cy HBM/L2 latency hides under the 32KB
// LDS stage + barrier) -> MFMA loop is pure LDS-B + MFMA.
// K/V sections process COMPACT rows only (gather via g_inv); K stride
// PT32 so k2's 32-wide tiles are fully initialized (pad rows = row-0 K,
// killed by the -1e30 bias).
// Layouts: q [nh][320][32]; k [nh][PT32][32]; v [nh][32][CP8].
// =====================================================================
__global__ __launch_bounds__(256, 4) void k1_qkv(
    const unsigned short* __restrict__ znws, const float* __restrict__ b_qkv,
    unsigned short* __restrict__ qws, unsigned short* __restrict__ kws,
    unsigned short* __restrict__ vws)
{
    __shared__ unsigned short ldsb[17408];  // 34816B: W frags (32KB), then tr [128][132]
    const int tid = threadIdx.x;
    const int bx = blockIdx.x;
    const int sect = bx % 3;          // 0=q 1=k 2=v
    const int mbase = (bx / 3) * 128;
    const int lane = tid & 63;
    const int wid = tid >> 6;
    const int qn = lane & 15, gd = lane >> 4;

    const int cnt = __builtin_amdgcn_readfirstlane(g_cnt);
    const int PT32 = (cnt + 31) & ~31;
    const int CP8  = (cnt + 7) & ~7;
    const int stride = (sect == 0) ? LQ : ((sect == 1) ? PT32 : CP8);
    const int rows_total = NSEQ * stride;
    if (mbase >= rows_total) return;

    // stage this section's W chunk (32KB, fragment-ordered) into LDS
    {
        const uint4* src = (const uint4*)g_wbf + sect * 2048;
        uint4* dst = (uint4*)ldsb;
        #pragma unroll
        for (int i = 0; i < 8; ++i) dst[tid + i * 256] = src[tid + i * 256];
    }

    const int n0 = mbase / stride;
    const int s0 = mbase - n0 * stride;

    // A-frag source rows (compact gather for k/v sections)
    int arow[2];
    #pragma unroll
    for (int rg = 0; rg < 2; ++rg) {
        const int off = wid * 32 + rg * 16 + qn;
        int n = n0, s = s0 + off;
        while (s >= stride) { s -= stride; ++n; }
        int grow = n * LQ + ((sect == 0) ? s : g_inv[s]);
        if (mbase + off >= rows_total) grow = 0;     // guarded at store time
        arow[rg] = grow;
    }

    // prefetch ALL A-frags now -- latency hides under staging + barrier
    FragU afAll[2][4];
    #pragma unroll
    for (int rg = 0; rg < 2; ++rg)
        #pragma unroll
        for (int kt = 0; kt < 4; ++kt)
            afAll[rg][kt].v = *(const bf16x8*)&znws[(size_t)arow[rg] * DDIM + kt * 32 + gd * 8];

    __syncthreads();   // W staged

    const f32x4 zero4 = {0.f, 0.f, 0.f, 0.f};
    f32x4 acc[2][8];
    #pragma unroll
    for (int rg = 0; rg < 2; ++rg)
        #pragma unroll
        for (int nt = 0; nt < 8; ++nt) acc[rg][nt] = zero4;

    #pragma unroll
    for (int kt = 0; kt < 4; ++kt) {
        #pragma unroll
        for (int nt = 0; nt < 8; ++nt) {
            FragU bf;
            bf.v = *(const bf16x8*)&ldsb[((kt * 8 + nt) * 64 + lane) * 8];
            #pragma unroll
            for (int rg = 0; rg < 2; ++rg)
                acc[rg][nt] = __builtin_amdgcn_mfma_f32_16x16x32_bf16(afAll[rg][kt].v, bf.v, acc[rg][nt], 0, 0, 0);
        }
    }

    float bq[8];
    #pragma unroll
    for (int nt = 0; nt < 8; ++nt) bq[nt] = b_qkv[sect * 128 + nt * 16 + qn];
    const float sc = (sect == 0) ? QSC2 : 1.0f;

    __syncthreads();   // all waves done reading W LDS
    unsigned short* tr = ldsb;  // [128][132] (q/k: [row][col], v: [col][row])

    if (sect < 2) {
        #pragma unroll
        for (int rg = 0; rg < 2; ++rg) {
            #pragma unroll
            for (int r = 0; r < 4; ++r) {
                const int row = wid * 32 + rg * 16 + 4 * gd + r;
                #pragma unroll
                for (int nt = 0; nt < 8; ++nt) {
                    const int col = nt * 16 + qn;
                    tr[row * 132 + col] = f2bf((acc[rg][nt][r] + bq[nt]) * sc);
                }
            }
        }
    } else {
        // v: tr[col][row], rows 4*gd..+3 contiguous -> one uint2 (4 bf16)
        #pragma unroll
        for (int rg = 0; rg < 2; ++rg) {
            const int row0 = wid * 32 + rg * 16 + 4 * gd;
            #pragma unroll
            for (int nt = 0; nt < 8; ++nt) {
                const int col = nt * 16 + qn;
                uint2 pv;
                pv.x = pack2(acc[rg][nt][0] + bq[nt], acc[rg][nt][1] + bq[nt]);
                pv.y = pack2(acc[rg][nt][2] + bq[nt], acc[rg][nt][3] + bq[nt]);
                *(uint2*)&tr[col * 132 + row0] = pv;
            }
        }
    }
    __syncthreads();

    // wave-per-head coalesced stores (head h = wid)
    if (sect < 2) {
        unsigned short* dst = (sect == 0) ? qws : kws;
        #pragma unroll 1
        for (int k16 = 0; k16 < 16; ++k16) {
            const int o2 = lane * 4 + k16 * 256;     // [128 rows][32 d] per head(wid)
            const int i_loc = o2 >> 5, d = o2 & 31;
            if (mbase + i_loc < rows_total) {
                int n = n0, s = s0 + i_loc;
                while (s >= stride) { s -= stride; ++n; }
                const ushort4 val = *(const ushort4*)&tr[i_loc * 132 + wid * 32 + d];
                *(ushort4*)&dst[((size_t)(n * NH + wid) * LQ + s) * DHD + d] = val;
            }
        }
    } else {
        #pragma unroll 1
        for (int k16 = 0; k16 < 16; ++k16) {
            const int o2 = lane * 4 + k16 * 256;     // [32 d][128 rows]
            const int d = o2 >> 7, i_loc = o2 & 127;
            if (mbase + i_loc < rows_total) {
                int n = n0, s = s0 + i_loc;
                while (s >= stride) { s -= stride; ++n; }
                const ushort4 val = *(const ushort4*)&tr[(wid * 32 + d) * 132 + i_loc];
                *(ushort4*)&vws[(size_t)(n * NH + wid) * (DHD * LQ) + d * CP8 + s] = val;
            }
        }
    }
}

// =====================================================================
// K2: MFMA attention, 32x32x16, ZERO LDS, zero bpermute.
// Grid 2560 (bx = nh*2 + half), block 320 (5 waves); each wave owns a
// 32-query tile. Round-6: one-tile K/V software pipeline (load kt+1's
// fragments into shadow regs before computing kt -> L1/L2 latency off
// the critical path). P->PV A-operand via 8 cvt_pk + 4 permlane32_swap.
// Online softmax with defer-max (THR=8, log2 domain). Boundary tile
// folds -1e30 into MFMA C; pad K slots (< PT32) hold row-0 K.
// =====================================================================
__global__ __launch_bounds__(320, 4) void k2_attn_mfma(
    const unsigned short* __restrict__ qws, const unsigned short* __restrict__ kws,
    const unsigned short* __restrict__ vtws, unsigned short* __restrict__ ows)
{
    const int tid = threadIdx.x;
    const int bx = blockIdx.x;
    const int nh = bx >> 1;
    const int lane = tid & 63;
    const int wid = tid >> 6;              // 0..4
    const int qt = (bx & 1) * 5 + wid;     // 32-query tile, 0..9
    const int qc = lane & 31;              // score col (q); O col (d)
    const int hf = lane >> 5;

    const int cnt = __builtin_amdgcn_readfirstlane(g_cnt);
    const int PT32 = (cnt + 31) & ~31;
    const int CP8  = (cnt + 7) & ~7;
    const int NT   = PT32 >> 5;

    const int n = nh >> 2, h = nh & 3;
    const unsigned short* kb = kws + (size_t)nh * LQ * DHD + hf * 8;
    const unsigned short* vb = vtws + (size_t)nh * DHD * LQ + (size_t)qc * CP8 + hf * 8;
    const unsigned short* qp = qws + ((size_t)nh * LQ + qt * 32 + qc) * DHD + hf * 8;

    FragU qf1, qf2;
    qf1.v = *(const bf16x8*)qp;
    qf2.v = *(const bf16x8*)(qp + 16);

    f32x16 o;
    #pragma unroll
    for (int r = 0; r < 16; ++r) o[r] = 0.f;
    float m_run = -1e30f, l_run = 0.f;

    // preload tile 0
    FragU kf1, kf2, vf1, vf2;
    {
        const unsigned short* kr = kb + (size_t)qc * DHD;
        kf1.v = *(const bf16x8*)kr;
        kf2.v = *(const bf16x8*)(kr + 16);
        vf1.v = *(const bf16x8*)(vb);
        vf2.v = *(const bf16x8*)(vb + 16);
    }

    #pragma unroll 1
    for (int kt = 0; kt < NT; ++kt) {
        // prefetch next tile's K/V into shadow regs (T14 issue-early)
        FragU kf1n, kf2n, vf1n, vf2n;
        if (kt + 1 < NT) {
            const unsigned short* krn = kb + (size_t)((kt + 1) * 32 + qc) * DHD;
            kf1n.v = *(const bf16x8*)krn;
            kf2n.v = *(const bf16x8*)(krn + 16);
            vf1n.v = *(const bf16x8*)(vb + (kt + 1) * 32);
            vf2n.v = *(const bf16x8*)(vb + (kt + 1) * 32 + 16);
        }

        f32x16 c0;
        #pragma unroll
        for (int r = 0; r < 16; ++r) c0[r] = 0.f;
        if ((kt + 1) * 32 > cnt) {                     // boundary: fold -inf bias
            #pragma unroll
            for (int r = 0; r < 16; ++r) {
                const int krow = kt * 32 + (r & 3) + 8 * (r >> 2) + 4 * hf;
                c0[r] = (krow < cnt) ? 0.f : -1e30f;
            }
        }
        f32x16 st = __builtin_amdgcn_mfma_f32_32x32x16_bf16(kf1.v, qf1.v, c0, 0, 0, 0);
        st = __builtin_amdgcn_mfma_f32_32x32x16_bf16(kf2.v, qf2.v, st, 0, 0, 0);

        float mh = st[0];
        #pragma unroll
        for (int r = 1; r < 16; ++r) mh = fmaxf(mh, st[r]);
        mh = fmaxf(mh, __shfl_xor(mh, 32, 64));
        if (!__all(mh <= m_run + 8.0f)) {              // defer-max (log2 domain)
            const float m_new = fmaxf(m_run, mh);
            const float scl = __builtin_amdgcn_exp2f(m_run - m_new);
            l_run *= scl;
            #pragma unroll
            for (int r = 0; r < 16; ++r) o[r] *= scl;
            m_run = m_new;
        }
        #pragma unroll
        for (int r = 0; r < 16; ++r) st[r] = __builtin_amdgcn_exp2f(st[r] - m_run);
        l_run += (((st[0] + st[1]) + (st[2] + st[3])) + ((st[4] + st[5]) + (st[6] + st[7])))
               + (((st[8] + st[9]) + (st[10] + st[11])) + ((st[12] + st[13]) + (st[14] + st[15])));

        // P -> A-operand fragments (rows=q, k = hf*8..+7 per lane)
        unsigned int a01 = pack2(st[0], st[1]), a23 = pack2(st[2], st[3]);
        unsigned int a45 = pack2(st[4], st[5]), a67 = pack2(st[6], st[7]);
        pl32swap(a01, a45);   // a01 = k(+0,+1), a45 = k(+4,+5) per half
        pl32swap(a23, a67);
        FragU pa1;
        pa1.u[0] = a01; pa1.u[1] = a23; pa1.u[2] = a45; pa1.u[3] = a67;
        o = __builtin_amdgcn_mfma_f32_32x32x16_bf16(pa1.v, vf1.v, o, 0, 0, 0);

        unsigned int b01 = pack2(st[8], st[9]),  b23 = pack2(st[10], st[11]);
        unsigned int b45 = pack2(st[12], st[13]), b67 = pack2(st[14], st[15]);
        pl32swap(b01, b45);
        pl32swap(b23, b67);
        FragU pa2;
        pa2.u[0] = b01; pa2.u[1] = b23; pa2.u[2] = b45; pa2.u[3] = b67;
        o = __builtin_amdgcn_mfma_f32_32x32x16_bf16(pa2.v, vf2.v, o, 0, 0, 0);

        kf1 = kf1n; kf2 = kf2n; vf1 = vf1n; vf2 = vf2n;
    }

    l_run += __shfl_xor(l_run, 32, 64);
    const float inv = 1.0f / l_run;

    #pragma unroll
    for (int r = 0; r < 16; ++r) {
        const int qloc = (r & 3) + 8 * (r >> 2) + 4 * hf;
        const float iv = __shfl(inv, qloc, 64);        // l for row-q of this reg
        const int qg = qt * 32 + qloc;
        ows[((size_t)(n * LQ + qg)) * DDIM + h * DHD + qc] = f2bf(o[r] * iv);
    }
}

// =====================================================================
// K3: out projection + residual, MFMA. Grid 800, block 256.
// Round-6: ALL 8 A-frags prefetched before the W-stage barrier
// (same T14 pattern as k1); w_out frags from fragment-ordered g_wbf.
// =====================================================================
__global__ __launch_bounds__(256, 4) void k3_out(
    const unsigned short* __restrict__ ows,
    const float* __restrict__ b_out, const float* __restrict__ z,
    float* __restrict__ out)
{
    __shared__ unsigned short ldsb[16384];  // 32KB W frags
    const int tid = threadIdx.x;
    const int mbase = blockIdx.x * 128;
    const int lane = tid & 63;
    const int wid = tid >> 6;
    const int qn = lane & 15, gd = lane >> 4;

    {
        const uint4* src = (const uint4*)g_wbf + 3 * 2048;
        uint4* dst = (uint4*)ldsb;
        #pragma unroll
        for (int i = 0; i < 8; ++i) dst[tid + i * 256] = src[tid + i * 256];
    }

    // prefetch ALL A-frags before the barrier (latency under staging)
    FragU afAll[2][4];
    #pragma unroll
    for (int rg = 0; rg < 2; ++rg)
        #pragma unroll
        for (int kt = 0; kt < 4; ++kt)
            afAll[rg][kt].v = *(const bf16x8*)&ows[
                (size_t)(mbase + wid * 32 + rg * 16 + qn) * DDIM + kt * 32 + gd * 8];

    __syncthreads();

    const f32x4 zero4 = {0.f, 0.f, 0.f, 0.f};
    f32x4 acc[2][8];
    #pragma unroll
    for (int rg = 0; rg < 2; ++rg)
        #pragma unroll
        for (int nt = 0; nt < 8; ++nt) acc[rg][nt] = zero4;

    #pragma unroll
    for (int kt = 0; kt < 4; ++kt) {
        #pragma unroll
        for (int nt = 0; nt < 8; ++nt) {
            FragU bf;
            bf.v = *(const bf16x8*)&ldsb[((kt * 8 + nt) * 64 + lane) * 8];
            #pragma unroll
            for (int rg = 0; rg < 2; ++rg)
                acc[rg][nt] = __builtin_amdgcn_mfma_f32_16x16x32_bf16(afAll[rg][kt].v, bf.v, acc[rg][nt], 0, 0, 0);
        }
    }

    float bb[8];
    #pragma unroll
    for (int nt = 0; nt < 8; ++nt) bb[nt] = b_out[nt * 16 + qn];

    #pragma unroll
    for (int rg = 0; rg < 2; ++rg) {
        #pragma unroll
        for (int r = 0; r < 4; ++r) {
            const int grow = mbase + wid * 32 + rg * 16 + 4 * gd + r;
            const float* zr = z + (size_t)grow * DDIM;
            float* outr = out + (size_t)grow * DDIM;
            #pragma unroll
            for (int nt = 0; nt < 8; ++nt) {
                const int cg = nt * 16 + qn;
                outr[cg] = acc[rg][nt][r] + bb[nt] + zr[cg];
            }
        }
    }
}

extern "C" void kernel_launch(void* const* d_in, const int* in_sizes, int n_in,
                              void* d_out, int out_size, void* d_ws, size_t ws_size,
                              hipStream_t stream) {
    const float* z     = (const float*)d_in[0];
    const int*   mask  = (const int*)d_in[1];
    const float* ln_g  = (const float*)d_in[2];
    const float* ln_b  = (const float*)d_in[3];
    const float* w_qkv = (const float*)d_in[4];
    const float* b_qkv = (const float*)d_in[5];
    const float* w_out = (const float*)d_in[6];
    const float* b_out = (const float*)d_in[7];
    float* out = (float*)d_out;

    unsigned short* ws = (unsigned short*)d_ws;
    const size_t qE = (size_t)NSEQ * NH * LQ * DHD;  // 13,107,200
    unsigned short* qws = ws;
    unsigned short* kws = qws + qE;
    unsigned short* vws = kws + qE;
    unsigned short* shared_rgn = vws + qE;           // NROWS*DDIM bf16
    unsigned int*   znws = (unsigned int*)shared_rgn;
    unsigned short* ows  = shared_rgn;

    hipLaunchKernelGGL(k0_ln, dim3(NROWS / 64), dim3(256), 0, stream,
                       z, ln_g, ln_b, znws, mask, w_qkv, w_out);
    hipLaunchKernelGGL(k1_qkv, dim3(2400), dim3(256), 0, stream,
                       (const unsigned short*)znws, b_qkv, qws, kws, vws);
    hipLaunchKernelGGL(k2_attn_mfma, dim3(2560), dim3(320), 0, stream,
                       qws, kws, vws, ows);
    hipLaunchKernelGGL(k3_out, dim3(800), dim3(256), 0, stream,
                       ows, b_out, z, out);
}

// Round 7
// 197.658 us; speedup vs baseline: 1.0015x; 1.0015x over previous
//
#include <hip/hip_runtime.h>

// Problem constants: B=1, L=320, D=128, H=4, DH=32
#define LQ 320
#define NSEQ 320
#define NROWS (NSEQ*LQ)   // 102400
#define DDIM 128
#define NH 4
#define DHD 32
#define LN_EPS 1e-5f
// 1/sqrt(32) * log2(e): folded into q so QK^T scores are in log2 domain
#define QSC2 0.25508652025545527f

typedef __bf16 bf16x8 __attribute__((ext_vector_type(8)));
typedef __bf16 bf16x2 __attribute__((ext_vector_type(2)));
typedef float f32x4 __attribute__((ext_vector_type(4)));
typedef float f32x16 __attribute__((ext_vector_type(16)));
union FragU { unsigned int u[4]; bf16x8 v; };

// key-compaction tables (mask is over keys, shared by all rows)
__device__ int g_inv[LQ];     // compact slot -> key position (pad slots -> 0)
__device__ int g_cnt;         // number of kept keys
// pre-converted bf16 weights in MFMA FRAGMENT order:
// uint4 chunk cid = ((s4*4 + kt)*8 + nt)*64 + lane holds
// W row (s4*128 + nt*16 + (lane&15)), cols kt*32 + (lane>>4)*8 .. +7.
// s4: 0,1,2 = w_qkv q/k/v chunks, 3 = w_out.
__device__ __align__(16) unsigned short g_wbf[512 * DDIM];

// native bf16 converts: compiler lowers paired casts to v_cvt_pk_bf16_f32
__device__ inline unsigned short f2bf(float f) {
    return __builtin_bit_cast(unsigned short, (__bf16)f);
}
__device__ inline unsigned int pack2(float a, float b) {
    bf16x2 t;
    t[0] = (__bf16)a;
    t[1] = (__bf16)b;
    return __builtin_bit_cast(unsigned int, t);
}
// 2x2 lane-block transpose: a <- [a.lo | b.lo], b <- [a.hi | b.hi]
__device__ inline void pl32swap(unsigned int &a, unsigned int &b) {
    asm volatile("v_permlane32_swap_b32 %0, %1" : "+v"(a), "+v"(b));
}

// =====================================================================
// K0: LayerNorm -> zn bf16 [row][128]. Grid 1600, block 256.
// Side jobs: block 0 wave 0: mask scan -> g_inv / g_cnt;
// blocks 1..32: W fp32 -> bf16 into g_wbf in FRAGMENT order.
// =====================================================================
__global__ __launch_bounds__(256) void k0_ln(
    const float* __restrict__ z, const float* __restrict__ ln_g, const float* __restrict__ ln_b,
    unsigned int* __restrict__ znws, const int* __restrict__ mask,
    const float* __restrict__ w_qkv, const float* __restrict__ w_out)
{
    const int tid = threadIdx.x;
    const int bx = blockIdx.x;
    const int rowbase = bx * 64;
    const int lane = tid & 63;
    const int wid = tid >> 6;

    if (bx == 0) {
        if (tid < 64) {
            int carry = 0;
            #pragma unroll 1
            for (int c = 0; c < 5; ++c) {
                const int i = c * 64 + tid;
                const int m = (mask[i] > 0) ? 1 : 0;
                int v = m;
                #pragma unroll
                for (int off = 1; off < 64; off <<= 1) {
                    const int o = __shfl_up(v, off, 64);
                    if (tid >= off) v += o;
                }
                v += carry;
                if (m) g_inv[v - 1] = i;
                carry = __shfl(v, 63, 64);
            }
            if (tid == 0) g_cnt = carry;
            for (int s = carry + tid; s < LQ; s += 64) g_inv[s] = 0;  // pad slots
        }
    } else if (bx <= 32) {
        // fragment-order W conversion: one uint4 chunk per thread
        const int cid = (bx - 1) * 256 + tid;   // 0..8191
        const int l2  = cid & 63;
        const int nt  = (cid >> 6) & 7;
        const int kt  = (cid >> 9) & 3;
        const int s4  = cid >> 11;              // 0..3
        const int qn2 = l2 & 15, gd2 = l2 >> 4;
        const int row = s4 * 128 + nt * 16 + qn2;       // 0..511
        const float4* src4 = (s4 < 3) ? (const float4*)w_qkv : (const float4*)w_out;
        const int rloc = (s4 < 3) ? row : (row - 384);
        const int fi = rloc * 32 + kt * 8 + gd2 * 2;
        const float4 a = src4[fi];
        const float4 b = src4[fi + 1];
        uint4 val;
        val.x = pack2(a.x, a.y);
        val.y = pack2(a.z, a.w);
        val.z = pack2(b.x, b.y);
        val.w = pack2(b.z, b.w);
        ((uint4*)g_wbf)[cid] = val;
    }

    const float g0 = ln_g[2 * lane], g1 = ln_g[2 * lane + 1];
    const float bb0 = ln_b[2 * lane], bb1 = ln_b[2 * lane + 1];
    #pragma unroll 1
    for (int r = wid; r < 64; r += 4) {
        const int row = rowbase + r;
        const float2 v = *(const float2*)(z + (size_t)row * DDIM + 2 * lane);
        float s = v.x + v.y;
        float s2 = v.x * v.x + v.y * v.y;
        #pragma unroll
        for (int off = 32; off > 0; off >>= 1) {
            s  += __shfl_xor(s, off, 64);
            s2 += __shfl_xor(s2, off, 64);
        }
        const float mu = s * (1.0f / 128.0f);
        const float var = s2 * (1.0f / 128.0f) - mu * mu;
        const float rs = rsqrtf(var + LN_EPS);
        znws[(size_t)row * 64 + lane] =
            pack2((v.x - mu) * rs * g0 + bb0, (v.y - mu) * rs * g1 + bb1);
    }
}

// =====================================================================
// K1: QKV GEMM, 3-way N-split. Grid 2400 (sect = bx%3, m = bx/3), block 256.
// A-frags prefetched before the W-stage barrier; B-frags via
// conflict-free ds_read_b128 from fragment-ordered g_wbf staged to LDS.
// K/V sections process COMPACT rows only (gather via g_inv); K stride
// PT32 (pad rows = row-0 K, killed by k2's -1e30 bias).
// Layouts: q [nh][320][32]; k [nh][PT32][32]; v [nh][32][CP8].
// =====================================================================
__global__ __launch_bounds__(256, 4) void k1_qkv(
    const unsigned short* __restrict__ znws, const float* __restrict__ b_qkv,
    unsigned short* __restrict__ qws, unsigned short* __restrict__ kws,
    unsigned short* __restrict__ vws)
{
    __shared__ unsigned short ldsb[17408];  // 34816B: W frags (32KB), then tr [128][132]
    const int tid = threadIdx.x;
    const int bx = blockIdx.x;
    const int sect = bx % 3;          // 0=q 1=k 2=v
    const int mbase = (bx / 3) * 128;
    const int lane = tid & 63;
    const int wid = tid >> 6;
    const int qn = lane & 15, gd = lane >> 4;

    const int cnt = __builtin_amdgcn_readfirstlane(g_cnt);
    const int PT32 = (cnt + 31) & ~31;
    const int CP8  = (cnt + 7) & ~7;
    const int stride = (sect == 0) ? LQ : ((sect == 1) ? PT32 : CP8);
    const int rows_total = NSEQ * stride;
    if (mbase >= rows_total) return;

    // stage this section's W chunk (32KB, fragment-ordered) into LDS
    {
        const uint4* src = (const uint4*)g_wbf + sect * 2048;
        uint4* dst = (uint4*)ldsb;
        #pragma unroll
        for (int i = 0; i < 8; ++i) dst[tid + i * 256] = src[tid + i * 256];
    }

    const int n0 = mbase / stride;
    const int s0 = mbase - n0 * stride;

    // A-frag source rows (compact gather for k/v sections)
    int arow[2];
    #pragma unroll
    for (int rg = 0; rg < 2; ++rg) {
        const int off = wid * 32 + rg * 16 + qn;
        int n = n0, s = s0 + off;
        while (s >= stride) { s -= stride; ++n; }
        int grow = n * LQ + ((sect == 0) ? s : g_inv[s]);
        if (mbase + off >= rows_total) grow = 0;     // guarded at store time
        arow[rg] = grow;
    }

    // prefetch ALL A-frags now -- latency hides under staging + barrier
    FragU afAll[2][4];
    #pragma unroll
    for (int rg = 0; rg < 2; ++rg)
        #pragma unroll
        for (int kt = 0; kt < 4; ++kt)
            afAll[rg][kt].v = *(const bf16x8*)&znws[(size_t)arow[rg] * DDIM + kt * 32 + gd * 8];

    __syncthreads();   // W staged

    const f32x4 zero4 = {0.f, 0.f, 0.f, 0.f};
    f32x4 acc[2][8];
    #pragma unroll
    for (int rg = 0; rg < 2; ++rg)
        #pragma unroll
        for (int nt = 0; nt < 8; ++nt) acc[rg][nt] = zero4;

    #pragma unroll
    for (int kt = 0; kt < 4; ++kt) {
        #pragma unroll
        for (int nt = 0; nt < 8; ++nt) {
            FragU bf;
            bf.v = *(const bf16x8*)&ldsb[((kt * 8 + nt) * 64 + lane) * 8];
            #pragma unroll
            for (int rg = 0; rg < 2; ++rg)
                acc[rg][nt] = __builtin_amdgcn_mfma_f32_16x16x32_bf16(afAll[rg][kt].v, bf.v, acc[rg][nt], 0, 0, 0);
        }
    }

    float bq[8];
    #pragma unroll
    for (int nt = 0; nt < 8; ++nt) bq[nt] = b_qkv[sect * 128 + nt * 16 + qn];
    const float sc = (sect == 0) ? QSC2 : 1.0f;

    __syncthreads();   // all waves done reading W LDS
    unsigned short* tr = ldsb;  // [128][132] (q/k: [row][col], v: [col][row])

    if (sect < 2) {
        #pragma unroll
        for (int rg = 0; rg < 2; ++rg) {
            #pragma unroll
            for (int r = 0; r < 4; ++r) {
                const int row = wid * 32 + rg * 16 + 4 * gd + r;
                #pragma unroll
                for (int nt = 0; nt < 8; ++nt) {
                    const int col = nt * 16 + qn;
                    tr[row * 132 + col] = f2bf((acc[rg][nt][r] + bq[nt]) * sc);
                }
            }
        }
    } else {
        // v: tr[col][row], rows 4*gd..+3 contiguous -> one uint2 (4 bf16)
        #pragma unroll
        for (int rg = 0; rg < 2; ++rg) {
            const int row0 = wid * 32 + rg * 16 + 4 * gd;
            #pragma unroll
            for (int nt = 0; nt < 8; ++nt) {
                const int col = nt * 16 + qn;
                uint2 pv;
                pv.x = pack2(acc[rg][nt][0] + bq[nt], acc[rg][nt][1] + bq[nt]);
                pv.y = pack2(acc[rg][nt][2] + bq[nt], acc[rg][nt][3] + bq[nt]);
                *(uint2*)&tr[col * 132 + row0] = pv;
            }
        }
    }
    __syncthreads();

    // wave-per-head coalesced stores (head h = wid)
    if (sect < 2) {
        unsigned short* dst = (sect == 0) ? qws : kws;
        #pragma unroll 1
        for (int k16 = 0; k16 < 16; ++k16) {
            const int o2 = lane * 4 + k16 * 256;     // [128 rows][32 d] per head(wid)
            const int i_loc = o2 >> 5, d = o2 & 31;
            if (mbase + i_loc < rows_total) {
                int n = n0, s = s0 + i_loc;
                while (s >= stride) { s -= stride; ++n; }
                const ushort4 val = *(const ushort4*)&tr[i_loc * 132 + wid * 32 + d];
                *(ushort4*)&dst[((size_t)(n * NH + wid) * LQ + s) * DHD + d] = val;
            }
        }
    } else {
        #pragma unroll 1
        for (int k16 = 0; k16 < 16; ++k16) {
            const int o2 = lane * 4 + k16 * 256;     // [32 d][128 rows]
            const int d = o2 >> 7, i_loc = o2 & 127;
            if (mbase + i_loc < rows_total) {
                int n = n0, s = s0 + i_loc;
                while (s >= stride) { s -= stride; ++n; }
                const ushort4 val = *(const ushort4*)&tr[(wid * 32 + d) * 132 + i_loc];
                *(ushort4*)&vws[(size_t)(n * NH + wid) * (DHD * LQ) + d * CP8 + s] = val;
            }
        }
    }
}

// =====================================================================
// K2: MFMA attention, 32x32x16, ZERO LDS, zero bpermute.
// Round-7: grid 1280 = one block per (n,h); 5 waves; each wave owns
// TWO 32-query tiles (wid, wid+5). K/V fragments loaded ONCE per key
// tile and shared by both q-tiles (K/V fetch + addressing halved);
// c0 bias computed once, shared; both QK MFMAs issue back-to-back so
// B's latency hides under A's softmax. P->PV A-operand via 8 cvt_pk +
// 4 permlane32_swap per tile. Online softmax with defer-max (THR=8,
// log2 domain). Pad K slots (< PT32) hold row-0 K, killed by bias.
// =====================================================================
__global__ __launch_bounds__(320, 3) void k2_attn_mfma(
    const unsigned short* __restrict__ qws, const unsigned short* __restrict__ kws,
    const unsigned short* __restrict__ vtws, unsigned short* __restrict__ ows)
{
    const int tid = threadIdx.x;
    const int nh = blockIdx.x;             // 0..1279
    const int lane = tid & 63;
    const int wid = tid >> 6;              // 0..4
    const int qc = lane & 31;              // score col (q); O col (d)
    const int hf = lane >> 5;

    const int cnt = __builtin_amdgcn_readfirstlane(g_cnt);
    const int PT32 = (cnt + 31) & ~31;
    const int CP8  = (cnt + 7) & ~7;
    const int NT   = PT32 >> 5;

    const int n = nh >> 2, h = nh & 3;
    const unsigned short* kb = kws + (size_t)nh * LQ * DHD + hf * 8;
    const unsigned short* vb = vtws + (size_t)nh * DHD * LQ + (size_t)qc * CP8 + hf * 8;

    const int qtA = wid, qtB = wid + 5;    // two 32-query tiles per wave
    const unsigned short* qpA = qws + ((size_t)nh * LQ + qtA * 32 + qc) * DHD + hf * 8;
    const unsigned short* qpB = qws + ((size_t)nh * LQ + qtB * 32 + qc) * DHD + hf * 8;

    FragU qfA1, qfA2, qfB1, qfB2;
    qfA1.v = *(const bf16x8*)qpA;
    qfA2.v = *(const bf16x8*)(qpA + 16);
    qfB1.v = *(const bf16x8*)qpB;
    qfB2.v = *(const bf16x8*)(qpB + 16);

    f32x16 oA, oB;
    #pragma unroll
    for (int r = 0; r < 16; ++r) { oA[r] = 0.f; oB[r] = 0.f; }
    float mA = -1e30f, lA = 0.f;
    float mB = -1e30f, lB = 0.f;

    #pragma unroll 1
    for (int kt = 0; kt < NT; ++kt) {
        const unsigned short* kr = kb + (size_t)(kt * 32 + qc) * DHD;
        FragU kf1, kf2, vf1, vf2;
        kf1.v = *(const bf16x8*)kr;
        kf2.v = *(const bf16x8*)(kr + 16);
        vf1.v = *(const bf16x8*)(vb + kt * 32);        // V[k 0..15 of tile][d]
        vf2.v = *(const bf16x8*)(vb + kt * 32 + 16);   // V[k 16..31][d]

        f32x16 c0;
        #pragma unroll
        for (int r = 0; r < 16; ++r) c0[r] = 0.f;
        if ((kt + 1) * 32 > cnt) {                     // boundary: fold -inf bias
            #pragma unroll
            for (int r = 0; r < 16; ++r) {
                const int krow = kt * 32 + (r & 3) + 8 * (r >> 2) + 4 * hf;
                c0[r] = (krow < cnt) ? 0.f : -1e30f;
            }
        }
        // both QK^T chains issue back-to-back (independent)
        f32x16 stA = __builtin_amdgcn_mfma_f32_32x32x16_bf16(kf1.v, qfA1.v, c0, 0, 0, 0);
        f32x16 stB = __builtin_amdgcn_mfma_f32_32x32x16_bf16(kf1.v, qfB1.v, c0, 0, 0, 0);
        stA = __builtin_amdgcn_mfma_f32_32x32x16_bf16(kf2.v, qfA2.v, stA, 0, 0, 0);
        stB = __builtin_amdgcn_mfma_f32_32x32x16_bf16(kf2.v, qfB2.v, stB, 0, 0, 0);

        // ---- softmax + PV, tile A ----
        {
            float mh = stA[0];
            #pragma unroll
            for (int r = 1; r < 16; ++r) mh = fmaxf(mh, stA[r]);
            mh = fmaxf(mh, __shfl_xor(mh, 32, 64));
            if (!__all(mh <= mA + 8.0f)) {             // defer-max (log2 domain)
                const float m_new = fmaxf(mA, mh);
                const float scl = __builtin_amdgcn_exp2f(mA - m_new);
                lA *= scl;
                #pragma unroll
                for (int r = 0; r < 16; ++r) oA[r] *= scl;
                mA = m_new;
            }
            #pragma unroll
            for (int r = 0; r < 16; ++r) stA[r] = __builtin_amdgcn_exp2f(stA[r] - mA);
            lA += (((stA[0] + stA[1]) + (stA[2] + stA[3])) + ((stA[4] + stA[5]) + (stA[6] + stA[7])))
                + (((stA[8] + stA[9]) + (stA[10] + stA[11])) + ((stA[12] + stA[13]) + (stA[14] + stA[15])));

            unsigned int a01 = pack2(stA[0], stA[1]), a23 = pack2(stA[2], stA[3]);
            unsigned int a45 = pack2(stA[4], stA[5]), a67 = pack2(stA[6], stA[7]);
            pl32swap(a01, a45);
            pl32swap(a23, a67);
            FragU pa1;
            pa1.u[0] = a01; pa1.u[1] = a23; pa1.u[2] = a45; pa1.u[3] = a67;
            oA = __builtin_amdgcn_mfma_f32_32x32x16_bf16(pa1.v, vf1.v, oA, 0, 0, 0);

            unsigned int b01 = pack2(stA[8], stA[9]),  b23 = pack2(stA[10], stA[11]);
            unsigned int b45 = pack2(stA[12], stA[13]), b67 = pack2(stA[14], stA[15]);
            pl32swap(b01, b45);
            pl32swap(b23, b67);
            FragU pa2;
            pa2.u[0] = b01; pa2.u[1] = b23; pa2.u[2] = b45; pa2.u[3] = b67;
            oA = __builtin_amdgcn_mfma_f32_32x32x16_bf16(pa2.v, vf2.v, oA, 0, 0, 0);
        }

        // ---- softmax + PV, tile B ----
        {
            float mh = stB[0];
            #pragma unroll
            for (int r = 1; r < 16; ++r) mh = fmaxf(mh, stB[r]);
            mh = fmaxf(mh, __shfl_xor(mh, 32, 64));
            if (!__all(mh <= mB + 8.0f)) {
                const float m_new = fmaxf(mB, mh);
                const float scl = __builtin_amdgcn_exp2f(mB - m_new);
                lB *= scl;
                #pragma unroll
                for (int r = 0; r < 16; ++r) oB[r] *= scl;
                mB = m_new;
            }
            #pragma unroll
            for (int r = 0; r < 16; ++r) stB[r] = __builtin_amdgcn_exp2f(stB[r] - mB);
            lB += (((stB[0] + stB[1]) + (stB[2] + stB[3])) + ((stB[4] + stB[5]) + (stB[6] + stB[7])))
                + (((stB[8] + stB[9]) + (stB[10] + stB[11])) + ((stB[12] + stB[13]) + (stB[14] + stB[15])));

            unsigned int a01 = pack2(stB[0], stB[1]), a23 = pack2(stB[2], stB[3]);
            unsigned int a45 = pack2(stB[4], stB[5]), a67 = pack2(stB[6], stB[7]);
            pl32swap(a01, a45);
            pl32swap(a23, a67);
            FragU pa1;
            pa1.u[0] = a01; pa1.u[1] = a23; pa1.u[2] = a45; pa1.u[3] = a67;
            oB = __builtin_amdgcn_mfma_f32_32x32x16_bf16(pa1.v, vf1.v, oB, 0, 0, 0);

            unsigned int b01 = pack2(stB[8], stB[9]),  b23 = pack2(stB[10], stB[11]);
            unsigned int b45 = pack2(stB[12], stB[13]), b67 = pack2(stB[14], stB[15]);
            pl32swap(b01, b45);
            pl32swap(b23, b67);
            FragU pa2;
            pa2.u[0] = b01; pa2.u[1] = b23; pa2.u[2] = b45; pa2.u[3] = b67;
            oB = __builtin_amdgcn_mfma_f32_32x32x16_bf16(pa2.v, vf2.v, oB, 0, 0, 0);
        }
    }

    lA += __shfl_xor(lA, 32, 64);
    lB += __shfl_xor(lB, 32, 64);
    const float invA = 1.0f / lA;
    const float invB = 1.0f / lB;

    #pragma unroll
    for (int r = 0; r < 16; ++r) {
        const int qloc = (r & 3) + 8 * (r >> 2) + 4 * hf;
        const float ivA = __shfl(invA, qloc, 64);
        const float ivB = __shfl(invB, qloc, 64);
        ows[((size_t)(n * LQ + qtA * 32 + qloc)) * DDIM + h * DHD + qc] = f2bf(oA[r] * ivA);
        ows[((size_t)(n * LQ + qtB * 32 + qloc)) * DDIM + h * DHD + qc] = f2bf(oB[r] * ivB);
    }
}

// =====================================================================
// K3: out projection + residual, MFMA. Grid 800, block 256.
// A-frags prefetched before the W-stage barrier; w_out frags from
// fragment-ordered g_wbf (chunk 3) via conflict-free ds_read_b128.
// =====================================================================
__global__ __launch_bounds__(256, 4) void k3_out(
    const unsigned short* __restrict__ ows,
    const float* __restrict__ b_out, const float* __restrict__ z,
    float* __restrict__ out)
{
    __shared__ unsigned short ldsb[16384];  // 32KB W frags
    const int tid = threadIdx.x;
    const int mbase = blockIdx.x * 128;
    const int lane = tid & 63;
    const int wid = tid >> 6;
    const int qn = lane & 15, gd = lane >> 4;

    {
        const uint4* src = (const uint4*)g_wbf + 3 * 2048;
        uint4* dst = (uint4*)ldsb;
        #pragma unroll
        for (int i = 0; i < 8; ++i) dst[tid + i * 256] = src[tid + i * 256];
    }

    // prefetch ALL A-frags before the barrier (latency under staging)
    FragU afAll[2][4];
    #pragma unroll
    for (int rg = 0; rg < 2; ++rg)
        #pragma unroll
        for (int kt = 0; kt < 4; ++kt)
            afAll[rg][kt].v = *(const bf16x8*)&ows[
                (size_t)(mbase + wid * 32 + rg * 16 + qn) * DDIM + kt * 32 + gd * 8];

    __syncthreads();

    const f32x4 zero4 = {0.f, 0.f, 0.f, 0.f};
    f32x4 acc[2][8];
    #pragma unroll
    for (int rg = 0; rg < 2; ++rg)
        #pragma unroll
        for (int nt = 0; nt < 8; ++nt) acc[rg][nt] = zero4;

    #pragma unroll
    for (int kt = 0; kt < 4; ++kt) {
        #pragma unroll
        for (int nt = 0; nt < 8; ++nt) {
            FragU bf;
            bf.v = *(const bf16x8*)&ldsb[((kt * 8 + nt) * 64 + lane) * 8];
            #pragma unroll
            for (int rg = 0; rg < 2; ++rg)
                acc[rg][nt] = __builtin_amdgcn_mfma_f32_16x16x32_bf16(afAll[rg][kt].v, bf.v, acc[rg][nt], 0, 0, 0);
        }
    }

    float bb[8];
    #pragma unroll
    for (int nt = 0; nt < 8; ++nt) bb[nt] = b_out[nt * 16 + qn];

    #pragma unroll
    for (int rg = 0; rg < 2; ++rg) {
        #pragma unroll
        for (int r = 0; r < 4; ++r) {
            const int grow = mbase + wid * 32 + rg * 16 + 4 * gd + r;
            const float* zr = z + (size_t)grow * DDIM;
            float* outr = out + (size_t)grow * DDIM;
            #pragma unroll
            for (int nt = 0; nt < 8; ++nt) {
                const int cg = nt * 16 + qn;
                outr[cg] = acc[rg][nt][r] + bb[nt] + zr[cg];
            }
        }
    }
}

extern "C" void kernel_launch(void* const* d_in, const int* in_sizes, int n_in,
                              void* d_out, int out_size, void* d_ws, size_t ws_size,
                              hipStream_t stream) {
    const float* z     = (const float*)d_in[0];
    const int*   mask  = (const int*)d_in[1];
    const float* ln_g  = (const float*)d_in[2];
    const float* ln_b  = (const float*)d_in[3];
    const float* w_qkv = (const float*)d_in[4];
    const float* b_qkv = (const float*)d_in[5];
    const float* w_out = (const float*)d_in[6];
    const float* b_out = (const float*)d_in[7];
    float* out = (float*)d_out;

    unsigned short* ws = (unsigned short*)d_ws;
    const size_t qE = (size_t)NSEQ * NH * LQ * DHD;  // 13,107,200
    unsigned short* qws = ws;
    unsigned short* kws = qws + qE;
    unsigned short* vws = kws + qE;
    unsigned short* shared_rgn = vws + qE;           // NROWS*DDIM bf16
    unsigned int*   znws = (unsigned int*)shared_rgn;
    unsigned short* ows  = shared_rgn;

    hipLaunchKernelGGL(k0_ln, dim3(NROWS / 64), dim3(256), 0, stream,
                       z, ln_g, ln_b, znws, mask, w_qkv, w_out);
    hipLaunchKernelGGL(k1_qkv, dim3(2400), dim3(256), 0, stream,
                       (const unsigned short*)znws, b_qkv, qws, kws, vws);
    hipLaunchKernelGGL(k2_attn_mfma, dim3(1280), dim3(320), 0, stream,
                       qws, kws, vws, ows);
    hipLaunchKernelGGL(k3_out, dim3(800), dim3(256), 0, stream,
                       ows, b_out, z, out);
}

// Round 8
// 197.240 us; speedup vs baseline: 1.0036x; 1.0021x over previous
//
#include <hip/hip_runtime.h>

// Problem constants: B=1, L=320, D=128, H=4, DH=32
#define LQ 320
#define NSEQ 320
#define NROWS (NSEQ*LQ)   // 102400
#define DDIM 128
#define NH 4
#define DHD 32
#define LN_EPS 1e-5f
// 1/sqrt(32) * log2(e): folded into q so QK^T scores are in log2 domain
#define QSC2 0.25508652025545527f

typedef __bf16 bf16x8 __attribute__((ext_vector_type(8)));
typedef __bf16 bf16x2 __attribute__((ext_vector_type(2)));
typedef float f32x4 __attribute__((ext_vector_type(4)));
typedef float f32x16 __attribute__((ext_vector_type(16)));
union FragU { unsigned int u[4]; bf16x8 v; };

// key-compaction tables (mask is over keys, shared by all rows)
__device__ int g_inv[LQ];     // compact slot -> key position (pad slots -> 0)
__device__ int g_cnt;         // number of kept keys
// pre-converted bf16 weights in MFMA FRAGMENT order:
// uint4 chunk cid = ((s4*4 + kt)*8 + nt)*64 + lane holds
// W row (s4*128 + nt*16 + (lane&15)), cols kt*32 + (lane>>4)*8 .. +7.
// s4: 0,1,2 = w_qkv q/k/v chunks, 3 = w_out.
__device__ __align__(16) unsigned short g_wbf[512 * DDIM];

// native bf16 converts: compiler lowers paired casts to v_cvt_pk_bf16_f32
__device__ inline unsigned short f2bf(float f) {
    return __builtin_bit_cast(unsigned short, (__bf16)f);
}
__device__ inline unsigned int pack2(float a, float b) {
    bf16x2 t;
    t[0] = (__bf16)a;
    t[1] = (__bf16)b;
    return __builtin_bit_cast(unsigned int, t);
}
// 2x2 lane-block transpose: a <- [a.lo | b.lo], b <- [a.hi | b.hi]
__device__ inline void pl32swap(unsigned int &a, unsigned int &b) {
    asm volatile("v_permlane32_swap_b32 %0, %1" : "+v"(a), "+v"(b));
}

// =====================================================================
// K0: LayerNorm -> zn bf16 [row][128]. Grid 1600, block 256.
// Side jobs: block 0 wave 0: mask scan -> g_inv / g_cnt;
// blocks 1..32: W fp32 -> bf16 into g_wbf in FRAGMENT order.
// =====================================================================
__global__ __launch_bounds__(256) void k0_ln(
    const float* __restrict__ z, const float* __restrict__ ln_g, const float* __restrict__ ln_b,
    unsigned int* __restrict__ znws, const int* __restrict__ mask,
    const float* __restrict__ w_qkv, const float* __restrict__ w_out)
{
    const int tid = threadIdx.x;
    const int bx = blockIdx.x;
    const int rowbase = bx * 64;
    const int lane = tid & 63;
    const int wid = tid >> 6;

    if (bx == 0) {
        if (tid < 64) {
            int carry = 0;
            #pragma unroll 1
            for (int c = 0; c < 5; ++c) {
                const int i = c * 64 + tid;
                const int m = (mask[i] > 0) ? 1 : 0;
                int v = m;
                #pragma unroll
                for (int off = 1; off < 64; off <<= 1) {
                    const int o = __shfl_up(v, off, 64);
                    if (tid >= off) v += o;
                }
                v += carry;
                if (m) g_inv[v - 1] = i;
                carry = __shfl(v, 63, 64);
            }
            if (tid == 0) g_cnt = carry;
            for (int s = carry + tid; s < LQ; s += 64) g_inv[s] = 0;  // pad slots
        }
    } else if (bx <= 32) {
        // fragment-order W conversion: one uint4 chunk per thread
        const int cid = (bx - 1) * 256 + tid;   // 0..8191
        const int l2  = cid & 63;
        const int nt  = (cid >> 6) & 7;
        const int kt  = (cid >> 9) & 3;
        const int s4  = cid >> 11;              // 0..3
        const int qn2 = l2 & 15, gd2 = l2 >> 4;
        const int row = s4 * 128 + nt * 16 + qn2;       // 0..511
        const float4* src4 = (s4 < 3) ? (const float4*)w_qkv : (const float4*)w_out;
        const int rloc = (s4 < 3) ? row : (row - 384);
        const int fi = rloc * 32 + kt * 8 + gd2 * 2;
        const float4 a = src4[fi];
        const float4 b = src4[fi + 1];
        uint4 val;
        val.x = pack2(a.x, a.y);
        val.y = pack2(a.z, a.w);
        val.z = pack2(b.x, b.y);
        val.w = pack2(b.z, b.w);
        ((uint4*)g_wbf)[cid] = val;
    }

    const float g0 = ln_g[2 * lane], g1 = ln_g[2 * lane + 1];
    const float bb0 = ln_b[2 * lane], bb1 = ln_b[2 * lane + 1];
    #pragma unroll 1
    for (int r = wid; r < 64; r += 4) {
        const int row = rowbase + r;
        const float2 v = *(const float2*)(z + (size_t)row * DDIM + 2 * lane);
        float s = v.x + v.y;
        float s2 = v.x * v.x + v.y * v.y;
        #pragma unroll
        for (int off = 32; off > 0; off >>= 1) {
            s  += __shfl_xor(s, off, 64);
            s2 += __shfl_xor(s2, off, 64);
        }
        const float mu = s * (1.0f / 128.0f);
        const float var = s2 * (1.0f / 128.0f) - mu * mu;
        const float rs = rsqrtf(var + LN_EPS);
        znws[(size_t)row * 64 + lane] =
            pack2((v.x - mu) * rs * g0 + bb0, (v.y - mu) * rs * g1 + bb1);
    }
}

// =====================================================================
// K1: QKV GEMM, 3-way N-split. Grid 2400 (sect = bx%3, m = bx/3), block 256.
// A-frags prefetched before the W-stage barrier; B-frags via
// conflict-free ds_read_b128 from fragment-ordered g_wbf staged to LDS.
// K/V sections process COMPACT rows only (gather via g_inv).
// Round-8: V layout blocked [kblk=key/8][32 d][8 key] per (n,h), stride
// PT32 (pad slots = row-0 V, killed by P=0) -> k1 v-stores AND k2
// v-loads fully coalesced.
// Layouts: q [nh][320][32]; k [nh][PT32][32]; v [nh][PT32/8][32][8].
// =====================================================================
__global__ __launch_bounds__(256, 4) void k1_qkv(
    const unsigned short* __restrict__ znws, const float* __restrict__ b_qkv,
    unsigned short* __restrict__ qws, unsigned short* __restrict__ kws,
    unsigned short* __restrict__ vws)
{
    __shared__ unsigned short ldsb[17408];  // 34816B: W frags (32KB), then tr [128][132]
    const int tid = threadIdx.x;
    const int bx = blockIdx.x;
    const int sect = bx % 3;          // 0=q 1=k 2=v
    const int mbase = (bx / 3) * 128;
    const int lane = tid & 63;
    const int wid = tid >> 6;
    const int qn = lane & 15, gd = lane >> 4;

    const int cnt = __builtin_amdgcn_readfirstlane(g_cnt);
    const int PT32 = (cnt + 31) & ~31;
    const int stride = (sect == 0) ? LQ : PT32;
    const int rows_total = NSEQ * stride;
    if (mbase >= rows_total) return;

    // stage this section's W chunk (32KB, fragment-ordered) into LDS
    {
        const uint4* src = (const uint4*)g_wbf + sect * 2048;
        uint4* dst = (uint4*)ldsb;
        #pragma unroll
        for (int i = 0; i < 8; ++i) dst[tid + i * 256] = src[tid + i * 256];
    }

    const int n0 = mbase / stride;
    const int s0 = mbase - n0 * stride;

    // A-frag source rows (compact gather for k/v sections)
    int arow[2];
    #pragma unroll
    for (int rg = 0; rg < 2; ++rg) {
        const int off = wid * 32 + rg * 16 + qn;
        int n = n0, s = s0 + off;
        while (s >= stride) { s -= stride; ++n; }
        int grow = n * LQ + ((sect == 0) ? s : g_inv[s]);
        if (mbase + off >= rows_total) grow = 0;     // guarded at store time
        arow[rg] = grow;
    }

    // prefetch ALL A-frags now -- latency hides under staging + barrier
    FragU afAll[2][4];
    #pragma unroll
    for (int rg = 0; rg < 2; ++rg)
        #pragma unroll
        for (int kt = 0; kt < 4; ++kt)
            afAll[rg][kt].v = *(const bf16x8*)&znws[(size_t)arow[rg] * DDIM + kt * 32 + gd * 8];

    __syncthreads();   // W staged

    const f32x4 zero4 = {0.f, 0.f, 0.f, 0.f};
    f32x4 acc[2][8];
    #pragma unroll
    for (int rg = 0; rg < 2; ++rg)
        #pragma unroll
        for (int nt = 0; nt < 8; ++nt) acc[rg][nt] = zero4;

    #pragma unroll
    for (int kt = 0; kt < 4; ++kt) {
        #pragma unroll
        for (int nt = 0; nt < 8; ++nt) {
            FragU bf;
            bf.v = *(const bf16x8*)&ldsb[((kt * 8 + nt) * 64 + lane) * 8];
            #pragma unroll
            for (int rg = 0; rg < 2; ++rg)
                acc[rg][nt] = __builtin_amdgcn_mfma_f32_16x16x32_bf16(afAll[rg][kt].v, bf.v, acc[rg][nt], 0, 0, 0);
        }
    }

    float bq[8];
    #pragma unroll
    for (int nt = 0; nt < 8; ++nt) bq[nt] = b_qkv[sect * 128 + nt * 16 + qn];
    const float sc = (sect == 0) ? QSC2 : 1.0f;

    __syncthreads();   // all waves done reading W LDS
    unsigned short* tr = ldsb;  // [128][132] (q/k: [row][col], v: [col][row])

    if (sect < 2) {
        #pragma unroll
        for (int rg = 0; rg < 2; ++rg) {
            #pragma unroll
            for (int r = 0; r < 4; ++r) {
                const int row = wid * 32 + rg * 16 + 4 * gd + r;
                #pragma unroll
                for (int nt = 0; nt < 8; ++nt) {
                    const int col = nt * 16 + qn;
                    tr[row * 132 + col] = f2bf((acc[rg][nt][r] + bq[nt]) * sc);
                }
            }
        }
    } else {
        // v: tr[col][row], rows 4*gd..+3 contiguous -> one uint2 (4 bf16)
        #pragma unroll
        for (int rg = 0; rg < 2; ++rg) {
            const int row0 = wid * 32 + rg * 16 + 4 * gd;
            #pragma unroll
            for (int nt = 0; nt < 8; ++nt) {
                const int col = nt * 16 + qn;
                uint2 pv;
                pv.x = pack2(acc[rg][nt][0] + bq[nt], acc[rg][nt][1] + bq[nt]);
                pv.y = pack2(acc[rg][nt][2] + bq[nt], acc[rg][nt][3] + bq[nt]);
                *(uint2*)&tr[col * 132 + row0] = pv;
            }
        }
    }
    __syncthreads();

    // wave-per-head coalesced stores (head h = wid)
    if (sect < 2) {
        unsigned short* dst = (sect == 0) ? qws : kws;
        #pragma unroll 1
        for (int k16 = 0; k16 < 16; ++k16) {
            const int o2 = lane * 4 + k16 * 256;     // [128 rows][32 d] per head(wid)
            const int i_loc = o2 >> 5, d = o2 & 31;
            if (mbase + i_loc < rows_total) {
                int n = n0, s = s0 + i_loc;
                while (s >= stride) { s -= stride; ++n; }
                const ushort4 val = *(const ushort4*)&tr[i_loc * 132 + wid * 32 + d];
                *(ushort4*)&dst[((size_t)(n * NH + wid) * LQ + s) * DHD + d] = val;
            }
        }
    } else {
        // v blocked layout: one kblk (32 d x 8 key = 64 ushort4) per wave
        // per iteration -> fully contiguous 512B wave stores.
        const int k4 = (lane & 1) * 4;
        const int d  = (lane >> 1) & 31;
        #pragma unroll 1
        for (int k16 = 0; k16 < 16; ++k16) {     // local kblk
            const int i_loc = k16 * 8 + k4;
            if (mbase + i_loc < rows_total) {
                int n = n0, s = s0 + i_loc;      // s0, stride mult of 32 -> s&7 == k4
                while (s >= stride) { s -= stride; ++n; }
                const ushort4 val = *(const ushort4*)&tr[(wid * 32 + d) * 132 + i_loc];
                *(ushort4*)&vws[(size_t)(n * NH + wid) * (DHD * LQ)
                                + (((s >> 3) * DHD + d) << 3) + (s & 7)] = val;
            }
        }
    }
}

// =====================================================================
// K2: MFMA attention, 32x32x16, ZERO LDS, zero bpermute.
// Grid 1280 = one block per (n,h); 5 waves; each wave owns TWO
// 32-query tiles (wid, wid+5). K/V fragments loaded once per key tile,
// shared by both q-tiles. Round-8: V reads from blocked [kblk][32][8]
// layout -> each vf load is a fully-contiguous 1KB wave access (was
// 64 cachelines at 320B stride). P->PV A-operand via 8 cvt_pk +
// 4 permlane32_swap per tile. Online softmax with defer-max (THR=8,
// log2 domain). Pad K/V slots (< PT32) hold row-0 data, killed by bias.
// =====================================================================
__global__ __launch_bounds__(320, 3) void k2_attn_mfma(
    const unsigned short* __restrict__ qws, const unsigned short* __restrict__ kws,
    const unsigned short* __restrict__ vtws, unsigned short* __restrict__ ows)
{
    const int tid = threadIdx.x;
    const int nh = blockIdx.x;             // 0..1279
    const int lane = tid & 63;
    const int wid = tid >> 6;              // 0..4
    const int qc = lane & 31;              // score col (q); O col (d)
    const int hf = lane >> 5;

    const int cnt = __builtin_amdgcn_readfirstlane(g_cnt);
    const int PT32 = (cnt + 31) & ~31;
    const int NT   = PT32 >> 5;

    const int n = nh >> 2, h = nh & 3;
    const unsigned short* kb = kws + (size_t)nh * LQ * DHD + hf * 8;
    // blocked V: value V[k][d] at plane + ((k>>3)*32 + d)*8 + (k&7)
    const unsigned short* vb = vtws + (size_t)nh * DHD * LQ + qc * 8 + hf * 256;

    const int qtA = wid, qtB = wid + 5;    // two 32-query tiles per wave
    const unsigned short* qpA = qws + ((size_t)nh * LQ + qtA * 32 + qc) * DHD + hf * 8;
    const unsigned short* qpB = qws + ((size_t)nh * LQ + qtB * 32 + qc) * DHD + hf * 8;

    FragU qfA1, qfA2, qfB1, qfB2;
    qfA1.v = *(const bf16x8*)qpA;
    qfA2.v = *(const bf16x8*)(qpA + 16);
    qfB1.v = *(const bf16x8*)qpB;
    qfB2.v = *(const bf16x8*)(qpB + 16);

    f32x16 oA, oB;
    #pragma unroll
    for (int r = 0; r < 16; ++r) { oA[r] = 0.f; oB[r] = 0.f; }
    float mA = -1e30f, lA = 0.f;
    float mB = -1e30f, lB = 0.f;

    #pragma unroll 1
    for (int kt = 0; kt < NT; ++kt) {
        const unsigned short* kr = kb + (size_t)(kt * 32 + qc) * DHD;
        FragU kf1, kf2, vf1, vf2;
        kf1.v = *(const bf16x8*)kr;
        kf2.v = *(const bf16x8*)(kr + 16);
        vf1.v = *(const bf16x8*)(vb + kt * 1024);        // V[kt*32+hf*8+j][qc]
        vf2.v = *(const bf16x8*)(vb + kt * 1024 + 512);  // V[kt*32+16+hf*8+j][qc]

        f32x16 c0;
        #pragma unroll
        for (int r = 0; r < 16; ++r) c0[r] = 0.f;
        if ((kt + 1) * 32 > cnt) {                     // boundary: fold -inf bias
            #pragma unroll
            for (int r = 0; r < 16; ++r) {
                const int krow = kt * 32 + (r & 3) + 8 * (r >> 2) + 4 * hf;
                c0[r] = (krow < cnt) ? 0.f : -1e30f;
            }
        }
        // both QK^T chains issue back-to-back (independent)
        f32x16 stA = __builtin_amdgcn_mfma_f32_32x32x16_bf16(kf1.v, qfA1.v, c0, 0, 0, 0);
        f32x16 stB = __builtin_amdgcn_mfma_f32_32x32x16_bf16(kf1.v, qfB1.v, c0, 0, 0, 0);
        stA = __builtin_amdgcn_mfma_f32_32x32x16_bf16(kf2.v, qfA2.v, stA, 0, 0, 0);
        stB = __builtin_amdgcn_mfma_f32_32x32x16_bf16(kf2.v, qfB2.v, stB, 0, 0, 0);

        // ---- softmax + PV, tile A ----
        {
            float mh = stA[0];
            #pragma unroll
            for (int r = 1; r < 16; ++r) mh = fmaxf(mh, stA[r]);
            mh = fmaxf(mh, __shfl_xor(mh, 32, 64));
            if (!__all(mh <= mA + 8.0f)) {             // defer-max (log2 domain)
                const float m_new = fmaxf(mA, mh);
                const float scl = __builtin_amdgcn_exp2f(mA - m_new);
                lA *= scl;
                #pragma unroll
                for (int r = 0; r < 16; ++r) oA[r] *= scl;
                mA = m_new;
            }
            #pragma unroll
            for (int r = 0; r < 16; ++r) stA[r] = __builtin_amdgcn_exp2f(stA[r] - mA);
            lA += (((stA[0] + stA[1]) + (stA[2] + stA[3])) + ((stA[4] + stA[5]) + (stA[6] + stA[7])))
                + (((stA[8] + stA[9]) + (stA[10] + stA[11])) + ((stA[12] + stA[13]) + (stA[14] + stA[15])));

            unsigned int a01 = pack2(stA[0], stA[1]), a23 = pack2(stA[2], stA[3]);
            unsigned int a45 = pack2(stA[4], stA[5]), a67 = pack2(stA[6], stA[7]);
            pl32swap(a01, a45);
            pl32swap(a23, a67);
            FragU pa1;
            pa1.u[0] = a01; pa1.u[1] = a23; pa1.u[2] = a45; pa1.u[3] = a67;
            oA = __builtin_amdgcn_mfma_f32_32x32x16_bf16(pa1.v, vf1.v, oA, 0, 0, 0);

            unsigned int b01 = pack2(stA[8], stA[9]),  b23 = pack2(stA[10], stA[11]);
            unsigned int b45 = pack2(stA[12], stA[13]), b67 = pack2(stA[14], stA[15]);
            pl32swap(b01, b45);
            pl32swap(b23, b67);
            FragU pa2;
            pa2.u[0] = b01; pa2.u[1] = b23; pa2.u[2] = b45; pa2.u[3] = b67;
            oA = __builtin_amdgcn_mfma_f32_32x32x16_bf16(pa2.v, vf2.v, oA, 0, 0, 0);
        }

        // ---- softmax + PV, tile B ----
        {
            float mh = stB[0];
            #pragma unroll
            for (int r = 1; r < 16; ++r) mh = fmaxf(mh, stB[r]);
            mh = fmaxf(mh, __shfl_xor(mh, 32, 64));
            if (!__all(mh <= mB + 8.0f)) {
                const float m_new = fmaxf(mB, mh);
                const float scl = __builtin_amdgcn_exp2f(mB - m_new);
                lB *= scl;
                #pragma unroll
                for (int r = 0; r < 16; ++r) oB[r] *= scl;
                mB = m_new;
            }
            #pragma unroll
            for (int r = 0; r < 16; ++r) stB[r] = __builtin_amdgcn_exp2f(stB[r] - mB);
            lB += (((stB[0] + stB[1]) + (stB[2] + stB[3])) + ((stB[4] + stB[5]) + (stB[6] + stB[7])))
                + (((stB[8] + stB[9]) + (stB[10] + stB[11])) + ((stB[12] + stB[13]) + (stB[14] + stB[15])));

            unsigned int a01 = pack2(stB[0], stB[1]), a23 = pack2(stB[2], stB[3]);
            unsigned int a45 = pack2(stB[4], stB[5]), a67 = pack2(stB[6], stB[7]);
            pl32swap(a01, a45);
            pl32swap(a23, a67);
            FragU pa1;
            pa1.u[0] = a01; pa1.u[1] = a23; pa1.u[2] = a45; pa1.u[3] = a67;
            oB = __builtin_amdgcn_mfma_f32_32x32x16_bf16(pa1.v, vf1.v, oB, 0, 0, 0);

            unsigned int b01 = pack2(stB[8], stB[9]),  b23 = pack2(stB[10], stB[11]);
            unsigned int b45 = pack2(stB[12], stB[13]), b67 = pack2(stB[14], stB[15]);
            pl32swap(b01, b45);
            pl32swap(b23, b67);
            FragU pa2;
            pa2.u[0] = b01; pa2.u[1] = b23; pa2.u[2] = b45; pa2.u[3] = b67;
            oB = __builtin_amdgcn_mfma_f32_32x32x16_bf16(pa2.v, vf2.v, oB, 0, 0, 0);
        }
    }

    lA += __shfl_xor(lA, 32, 64);
    lB += __shfl_xor(lB, 32, 64);
    const float invA = 1.0f / lA;
    const float invB = 1.0f / lB;

    #pragma unroll
    for (int r = 0; r < 16; ++r) {
        const int qloc = (r & 3) + 8 * (r >> 2) + 4 * hf;
        const float ivA = __shfl(invA, qloc, 64);
        const float ivB = __shfl(invB, qloc, 64);
        ows[((size_t)(n * LQ + qtA * 32 + qloc)) * DDIM + h * DHD + qc] = f2bf(oA[r] * ivA);
        ows[((size_t)(n * LQ + qtB * 32 + qloc)) * DDIM + h * DHD + qc] = f2bf(oB[r] * ivB);
    }
}

// =====================================================================
// K3: out projection + residual, MFMA. Grid 800, block 256.
// A-frags prefetched before the W-stage barrier; w_out frags from
// fragment-ordered g_wbf (chunk 3) via conflict-free ds_read_b128.
// =====================================================================
__global__ __launch_bounds__(256, 4) void k3_out(
    const unsigned short* __restrict__ ows,
    const float* __restrict__ b_out, const float* __restrict__ z,
    float* __restrict__ out)
{
    __shared__ unsigned short ldsb[16384];  // 32KB W frags
    const int tid = threadIdx.x;
    const int mbase = blockIdx.x * 128;
    const int lane = tid & 63;
    const int wid = tid >> 6;
    const int qn = lane & 15, gd = lane >> 4;

    {
        const uint4* src = (const uint4*)g_wbf + 3 * 2048;
        uint4* dst = (uint4*)ldsb;
        #pragma unroll
        for (int i = 0; i < 8; ++i) dst[tid + i * 256] = src[tid + i * 256];
    }

    // prefetch ALL A-frags before the barrier (latency under staging)
    FragU afAll[2][4];
    #pragma unroll
    for (int rg = 0; rg < 2; ++rg)
        #pragma unroll
        for (int kt = 0; kt < 4; ++kt)
            afAll[rg][kt].v = *(const bf16x8*)&ows[
                (size_t)(mbase + wid * 32 + rg * 16 + qn) * DDIM + kt * 32 + gd * 8];

    __syncthreads();

    const f32x4 zero4 = {0.f, 0.f, 0.f, 0.f};
    f32x4 acc[2][8];
    #pragma unroll
    for (int rg = 0; rg < 2; ++rg)
        #pragma unroll
        for (int nt = 0; nt < 8; ++nt) acc[rg][nt] = zero4;

    #pragma unroll
    for (int kt = 0; kt < 4; ++kt) {
        #pragma unroll
        for (int nt = 0; nt < 8; ++nt) {
            FragU bf;
            bf.v = *(const bf16x8*)&ldsb[((kt * 8 + nt) * 64 + lane) * 8];
            #pragma unroll
            for (int rg = 0; rg < 2; ++rg)
                acc[rg][nt] = __builtin_amdgcn_mfma_f32_16x16x32_bf16(afAll[rg][kt].v, bf.v, acc[rg][nt], 0, 0, 0);
        }
    }

    float bb[8];
    #pragma unroll
    for (int nt = 0; nt < 8; ++nt) bb[nt] = b_out[nt * 16 + qn];

    #pragma unroll
    for (int rg = 0; rg < 2; ++rg) {
        #pragma unroll
        for (int r = 0; r < 4; ++r) {
            const int grow = mbase + wid * 32 + rg * 16 + 4 * gd + r;
            const float* zr = z + (size_t)grow * DDIM;
            float* outr = out + (size_t)grow * DDIM;
            #pragma unroll
            for (int nt = 0; nt < 8; ++nt) {
                const int cg = nt * 16 + qn;
                outr[cg] = acc[rg][nt][r] + bb[nt] + zr[cg];
            }
        }
    }
}

extern "C" void kernel_launch(void* const* d_in, const int* in_sizes, int n_in,
                              void* d_out, int out_size, void* d_ws, size_t ws_size,
                              hipStream_t stream) {
    const float* z     = (const float*)d_in[0];
    const int*   mask  = (const int*)d_in[1];
    const float* ln_g  = (const float*)d_in[2];
    const float* ln_b  = (const float*)d_in[3];
    const float* w_qkv = (const float*)d_in[4];
    const float* b_qkv = (const float*)d_in[5];
    const float* w_out = (const float*)d_in[6];
    const float* b_out = (const float*)d_in[7];
    float* out = (float*)d_out;

    unsigned short* ws = (unsigned short*)d_ws;
    const size_t qE = (size_t)NSEQ * NH * LQ * DHD;  // 13,107,200
    unsigned short* qws = ws;
    unsigned short* kws = qws + qE;
    unsigned short* vws = kws + qE;
    unsigned short* shared_rgn = vws + qE;           // NROWS*DDIM bf16
    unsigned int*   znws = (unsigned int*)shared_rgn;
    unsigned short* ows  = shared_rgn;

    hipLaunchKernelGGL(k0_ln, dim3(NROWS / 64), dim3(256), 0, stream,
                       z, ln_g, ln_b, znws, mask, w_qkv, w_out);
    hipLaunchKernelGGL(k1_qkv, dim3(2400), dim3(256), 0, stream,
                       (const unsigned short*)znws, b_qkv, qws, kws, vws);
    hipLaunchKernelGGL(k2_attn_mfma, dim3(1280), dim3(320), 0, stream,
                       qws, kws, vws, ows);
    hipLaunchKernelGGL(k3_out, dim3(800), dim3(256), 0, stream,
                       ows, b_out, z, out);
}